// Round 1
// baseline (1654.901 us; speedup 1.0000x reference)
//
#include <hip/hip_runtime.h>

#define N_NODES 50000
#define FEAT    64
#define HID     128
#define OUTD    128
#define N_EDGES 640000

// ws layout (floats):
//   deg  : [0, N)
//   agg1 : [N, N + N*64)
//   h    : [N+N*64, N+N*64+N*128)
//   agg2 : [N+N*64+N*128, N+N*64+2*N*128)
#define OFF_DEG  0
#define OFF_AGG1 (N_NODES)
#define OFF_H    (N_NODES + N_NODES*64)
#define OFF_AGG2 (N_NODES + N_NODES*64 + N_NODES*128)

// Layer-1 scatter: one thread per (edge, feature), feature dim = 64.
// Thread with f==0 also accumulates degree.
__global__ void scatter64_kernel(const int* __restrict__ src,
                                 const int* __restrict__ dst,
                                 const float* __restrict__ x,
                                 float* __restrict__ agg,
                                 float* __restrict__ deg) {
    long long i = (long long)blockIdx.x * blockDim.x + threadIdx.x;
    if (i >= (long long)N_EDGES * FEAT) return;
    int e = (int)(i >> 6);
    int f = (int)(i & 63);
    int d = dst[e];
    int s = src[e];
    atomicAdd(&agg[(long long)d * FEAT + f], x[(long long)s * FEAT + f]);
    if (f == 0) atomicAdd(&deg[d], 1.0f);
}

// Layer-2 scatter: one thread per (edge, feature), feature dim = 128.
__global__ void scatter128_kernel(const int* __restrict__ src,
                                  const int* __restrict__ dst,
                                  const float* __restrict__ h,
                                  float* __restrict__ agg) {
    long long i = (long long)blockIdx.x * blockDim.x + threadIdx.x;
    if (i >= (long long)N_EDGES * HID) return;
    int e = (int)(i >> 7);
    int f = (int)(i & 127);
    int d = dst[e];
    int s = src[e];
    atomicAdd(&agg[(long long)d * HID + f], h[(long long)s * HID + f]);
}

// Layer 1 linear: h = relu((agg1/deg) @ W1l^T + b1l + x @ W1r^T)
// One block (128 threads) per node; thread o computes output feature o.
__global__ __launch_bounds__(128) void lin1_kernel(
        const float* __restrict__ agg1, const float* __restrict__ deg,
        const float* __restrict__ x,
        const float* __restrict__ W1l, const float* __restrict__ b1l,
        const float* __restrict__ W1r,
        float* __restrict__ h) {
    int node = blockIdx.x;
    int o = threadIdx.x;
    __shared__ float sm[FEAT];
    __shared__ float sx[FEAT];
    float dinv = 1.0f / fmaxf(deg[node], 1.0f);
    if (o < FEAT) {
        sm[o] = agg1[(long long)node * FEAT + o] * dinv;
    } else {
        sx[o - FEAT] = x[(long long)node * FEAT + (o - FEAT)];
    }
    __syncthreads();
    float acc = b1l[o];
    const float* wl = W1l + (long long)o * FEAT;
    const float* wr = W1r + (long long)o * FEAT;
    #pragma unroll
    for (int k = 0; k < FEAT; k++) {
        acc += sm[k] * wl[k] + sx[k] * wr[k];
    }
    h[(long long)node * HID + o] = fmaxf(acc, 0.0f);
}

// Layer 2 linear: out = (agg2/deg) @ W2l^T + b2l + h @ W2r^T
__global__ __launch_bounds__(128) void lin2_kernel(
        const float* __restrict__ agg2, const float* __restrict__ deg,
        const float* __restrict__ h,
        const float* __restrict__ W2l, const float* __restrict__ b2l,
        const float* __restrict__ W2r,
        float* __restrict__ out) {
    int node = blockIdx.x;
    int o = threadIdx.x;
    __shared__ float sm[HID];
    __shared__ float sx[HID];
    float dinv = 1.0f / fmaxf(deg[node], 1.0f);
    sm[o] = agg2[(long long)node * HID + o] * dinv;
    sx[o] = h[(long long)node * HID + o];
    __syncthreads();
    float acc = b2l[o];
    const float* wl = W2l + (long long)o * HID;
    const float* wr = W2r + (long long)o * HID;
    #pragma unroll
    for (int k = 0; k < HID; k++) {
        acc += sm[k] * wl[k] + sx[k] * wr[k];
    }
    out[(long long)node * OUTD + o] = acc;
}

extern "C" void kernel_launch(void* const* d_in, const int* in_sizes, int n_in,
                              void* d_out, int out_size, void* d_ws, size_t ws_size,
                              hipStream_t stream) {
    const int*   edge_index = (const int*)d_in[0];   // [2, E]
    const float* emb        = (const float*)d_in[1]; // [N, 64]
    const float* W1l        = (const float*)d_in[2]; // [128, 64]
    const float* b1l        = (const float*)d_in[3]; // [128]
    const float* W1r        = (const float*)d_in[4]; // [128, 64]
    const float* W2l        = (const float*)d_in[5]; // [128, 128]
    const float* b2l        = (const float*)d_in[6]; // [128]
    const float* W2r        = (const float*)d_in[7]; // [128, 128]
    float* out = (float*)d_out;

    const int* src = edge_index;
    const int* dst = edge_index + N_EDGES;

    float* ws   = (float*)d_ws;
    float* deg  = ws + OFF_DEG;
    float* agg1 = ws + OFF_AGG1;
    float* h    = ws + OFF_H;
    float* agg2 = ws + OFF_AGG2;

    // Zero deg + agg1 (contiguous) and agg2. h is fully overwritten.
    hipMemsetAsync(deg,  0, (size_t)(N_NODES + N_NODES * FEAT) * sizeof(float), stream);
    hipMemsetAsync(agg2, 0, (size_t)N_NODES * HID * sizeof(float), stream);

    {
        long long total = (long long)N_EDGES * FEAT;
        int blocks = (int)((total + 255) / 256);
        scatter64_kernel<<<blocks, 256, 0, stream>>>(src, dst, emb, agg1, deg);
    }
    lin1_kernel<<<N_NODES, 128, 0, stream>>>(agg1, deg, emb, W1l, b1l, W1r, h);
    {
        long long total = (long long)N_EDGES * HID;
        int blocks = (int)((total + 255) / 256);
        scatter128_kernel<<<blocks, 256, 0, stream>>>(src, dst, h, agg2);
    }
    lin2_kernel<<<N_NODES, 128, 0, stream>>>(agg2, deg, h, W2l, b2l, W2r, out);
}

// Round 2
// 495.646 us; speedup vs baseline: 3.3389x; 3.3389x over previous
//
#include <hip/hip_runtime.h>

#define N_NODES 50000
#define FEAT    64
#define HID     128
#define N_EDGES 640000
#define NT      8      // nodes per lin block
#define NB      196    // scan blocks = ceil(50000/256)

// ---------------- weight transpose: out[k*128+o] = in[o*C+k] (R=128 fixed) --
__global__ void transpose_kernel(const float* __restrict__ in,
                                 float* __restrict__ out, int C, int total) {
    int id = blockIdx.x * blockDim.x + threadIdx.x;
    if (id >= total) return;
    int o = id & 127;
    int k = id >> 7;
    out[id] = in[o * C + k];
}

// ---------------- CSR build ------------------------------------------------
__global__ void hist_kernel(const int* __restrict__ dst, int* __restrict__ count) {
    int e = blockIdx.x * blockDim.x + threadIdx.x;
    if (e < N_EDGES) atomicAdd(&count[dst[e]], 1);
}

__global__ __launch_bounds__(256) void scan1_kernel(const int* __restrict__ count,
                                                    int* __restrict__ offset,
                                                    int* __restrict__ bsum) {
    __shared__ int tmp[256];
    int t = threadIdx.x;
    int i = blockIdx.x * 256 + t;
    int v = (i < N_NODES) ? count[i] : 0;
    tmp[t] = v;
    __syncthreads();
    for (int off = 1; off < 256; off <<= 1) {
        int add = (t >= off) ? tmp[t - off] : 0;
        __syncthreads();
        tmp[t] += add;
        __syncthreads();
    }
    if (i < N_NODES) offset[i] = tmp[t] - v;   // exclusive within block
    if (t == 255) bsum[blockIdx.x] = tmp[255];
}

__global__ __launch_bounds__(256) void scan2_kernel(const int* __restrict__ bsum,
                                                    int* __restrict__ boff) {
    __shared__ int tmp[256];
    int t = threadIdx.x;
    int v = (t < NB) ? bsum[t] : 0;
    tmp[t] = v;
    __syncthreads();
    for (int off = 1; off < 256; off <<= 1) {
        int add = (t >= off) ? tmp[t - off] : 0;
        __syncthreads();
        tmp[t] += add;
        __syncthreads();
    }
    if (t < NB) boff[t] = tmp[t] - v;          // exclusive block offsets
}

__global__ void scan3_kernel(int* __restrict__ offset, const int* __restrict__ boff) {
    int i = blockIdx.x * 256 + threadIdx.x;
    if (i < N_NODES) offset[i] += boff[blockIdx.x];
    if (i == 0) offset[N_NODES] = N_EDGES;
}

__global__ void fill_kernel(const int* __restrict__ src, const int* __restrict__ dst,
                            const int* __restrict__ offset, int* __restrict__ cursor,
                            int* __restrict__ esrc) {
    int e = blockIdx.x * blockDim.x + threadIdx.x;
    if (e >= N_EDGES) return;
    int d = dst[e];
    int slot = atomicAdd(&cursor[d], 1);
    esrc[offset[d] + slot] = src[e];
}

// ---------------- layer 1: fused mean-aggregate + dual linear + relu -------
// block = 256 threads, NT=8 nodes. Gather: wave w handles nodes {w, w+4}.
// Matmul: thread owns (node = t/32, outputs ob..ob+3), weights k-major.
__global__ __launch_bounds__(256) void lin1_kernel(
        const float* __restrict__ emb, const int* __restrict__ offset,
        const int* __restrict__ esrc,
        const float* __restrict__ WT1l, const float* __restrict__ b1l,
        const float* __restrict__ WT1r,
        float* __restrict__ h) {
    __shared__ float sm[NT][FEAT];
    __shared__ float sx[NT][FEAT];
    int t = threadIdx.x;
    int n0 = blockIdx.x * NT;
    int w = t >> 6;       // 0..3
    int f = t & 63;
    for (int p = 0; p < 2; ++p) {
        int r = p * 4 + w;
        int n = n0 + r;
        int beg = offset[n], end = offset[n + 1];
        float acc = 0.f;
        int i = beg;
        for (; i + 1 < end; i += 2) {
            int s0 = esrc[i], s1 = esrc[i + 1];
            acc += emb[s0 * FEAT + f] + emb[s1 * FEAT + f];
        }
        if (i < end) acc += emb[esrc[i] * FEAT + f];
        float dinv = 1.0f / fmaxf((float)(end - beg), 1.0f);
        sm[r][f] = acc * dinv;
        sx[r][f] = emb[n * FEAT + f];
    }
    __syncthreads();
    int r2 = t >> 5;           // node 0..7
    int ob = (t & 31) << 2;    // output base 0..124
    float4 acc = *(const float4*)&b1l[ob];
    #pragma unroll 4
    for (int k = 0; k < FEAT; k += 4) {
        float4 m4 = *(const float4*)&sm[r2][k];
        float4 x4 = *(const float4*)&sx[r2][k];
        float4 a0 = *(const float4*)&WT1l[(k + 0) * HID + ob];
        float4 a1 = *(const float4*)&WT1l[(k + 1) * HID + ob];
        float4 a2 = *(const float4*)&WT1l[(k + 2) * HID + ob];
        float4 a3 = *(const float4*)&WT1l[(k + 3) * HID + ob];
        float4 c0 = *(const float4*)&WT1r[(k + 0) * HID + ob];
        float4 c1 = *(const float4*)&WT1r[(k + 1) * HID + ob];
        float4 c2 = *(const float4*)&WT1r[(k + 2) * HID + ob];
        float4 c3 = *(const float4*)&WT1r[(k + 3) * HID + ob];
        acc.x += m4.x*a0.x + m4.y*a1.x + m4.z*a2.x + m4.w*a3.x
               + x4.x*c0.x + x4.y*c1.x + x4.z*c2.x + x4.w*c3.x;
        acc.y += m4.x*a0.y + m4.y*a1.y + m4.z*a2.y + m4.w*a3.y
               + x4.x*c0.y + x4.y*c1.y + x4.z*c2.y + x4.w*c3.y;
        acc.z += m4.x*a0.z + m4.y*a1.z + m4.z*a2.z + m4.w*a3.z
               + x4.x*c0.z + x4.y*c1.z + x4.z*c2.z + x4.w*c3.z;
        acc.w += m4.x*a0.w + m4.y*a1.w + m4.z*a2.w + m4.w*a3.w
               + x4.x*c0.w + x4.y*c1.w + x4.z*c2.w + x4.w*c3.w;
    }
    int n = n0 + r2;
    float4 o4;
    o4.x = fmaxf(acc.x, 0.f); o4.y = fmaxf(acc.y, 0.f);
    o4.z = fmaxf(acc.z, 0.f); o4.w = fmaxf(acc.w, 0.f);
    *(float4*)&h[n * HID + ob] = o4;
}

// ---------------- layer 2: fused mean-aggregate + dual linear --------------
__global__ __launch_bounds__(256) void lin2_kernel(
        const float* __restrict__ h, const int* __restrict__ offset,
        const int* __restrict__ esrc,
        const float* __restrict__ WT2l, const float* __restrict__ b2l,
        const float* __restrict__ WT2r,
        float* __restrict__ out) {
    __shared__ float sm[NT][HID];
    __shared__ float sx[NT][HID];
    int t = threadIdx.x;
    int n0 = blockIdx.x * NT;
    int g = t >> 7;        // 0..1 (128-lane group)
    int f = t & 127;
    for (int p = 0; p < 4; ++p) {
        int r = p * 2 + g;
        int n = n0 + r;
        int beg = offset[n], end = offset[n + 1];
        float acc = 0.f;
        int i = beg;
        for (; i + 1 < end; i += 2) {
            int s0 = esrc[i], s1 = esrc[i + 1];
            acc += h[s0 * HID + f] + h[s1 * HID + f];
        }
        if (i < end) acc += h[esrc[i] * HID + f];
        float dinv = 1.0f / fmaxf((float)(end - beg), 1.0f);
        sm[r][f] = acc * dinv;
        sx[r][f] = h[n * HID + f];
    }
    __syncthreads();
    int r2 = t >> 5;
    int ob = (t & 31) << 2;
    float4 acc = *(const float4*)&b2l[ob];
    #pragma unroll 4
    for (int k = 0; k < HID; k += 4) {
        float4 m4 = *(const float4*)&sm[r2][k];
        float4 x4 = *(const float4*)&sx[r2][k];
        float4 a0 = *(const float4*)&WT2l[(k + 0) * HID + ob];
        float4 a1 = *(const float4*)&WT2l[(k + 1) * HID + ob];
        float4 a2 = *(const float4*)&WT2l[(k + 2) * HID + ob];
        float4 a3 = *(const float4*)&WT2l[(k + 3) * HID + ob];
        float4 c0 = *(const float4*)&WT2r[(k + 0) * HID + ob];
        float4 c1 = *(const float4*)&WT2r[(k + 1) * HID + ob];
        float4 c2 = *(const float4*)&WT2r[(k + 2) * HID + ob];
        float4 c3 = *(const float4*)&WT2r[(k + 3) * HID + ob];
        acc.x += m4.x*a0.x + m4.y*a1.x + m4.z*a2.x + m4.w*a3.x
               + x4.x*c0.x + x4.y*c1.x + x4.z*c2.x + x4.w*c3.x;
        acc.y += m4.x*a0.y + m4.y*a1.y + m4.z*a2.y + m4.w*a3.y
               + x4.x*c0.y + x4.y*c1.y + x4.z*c2.y + x4.w*c3.y;
        acc.z += m4.x*a0.z + m4.y*a1.z + m4.z*a2.z + m4.w*a3.z
               + x4.x*c0.z + x4.y*c1.z + x4.z*c2.z + x4.w*c3.z;
        acc.w += m4.x*a0.w + m4.y*a1.w + m4.z*a2.w + m4.w*a3.w
               + x4.x*c0.w + x4.y*c1.w + x4.z*c2.w + x4.w*c3.w;
    }
    int n = n0 + r2;
    *(float4*)&out[n * HID + ob] = acc;
}

extern "C" void kernel_launch(void* const* d_in, const int* in_sizes, int n_in,
                              void* d_out, int out_size, void* d_ws, size_t ws_size,
                              hipStream_t stream) {
    const int*   edge_index = (const int*)d_in[0];   // [2, E]
    const float* emb        = (const float*)d_in[1]; // [N, 64]
    const float* W1l        = (const float*)d_in[2]; // [128, 64]
    const float* b1l        = (const float*)d_in[3]; // [128]
    const float* W1r        = (const float*)d_in[4]; // [128, 64]
    const float* W2l        = (const float*)d_in[5]; // [128, 128]
    const float* b2l        = (const float*)d_in[6]; // [128]
    const float* W2r        = (const float*)d_in[7]; // [128, 128]
    float* out = (float*)d_out;

    const int* src = edge_index;
    const int* dst = edge_index + N_EDGES;

    // ---- ws layout (ints then 16B-aligned floats), ~29 MB total ----
    int* iws    = (int*)d_ws;
    int* offset = iws;                 // 50001
    int* count  = iws + 50004;         // 50000
    int* cursor = iws + 100004;        // 50000 (contiguous with count)
    int* bsum   = iws + 150004;        // 256
    int* boff   = iws + 150260;        // 256
    int* esrc   = iws + 150516;        // 640000  (ends 790516)
    float* fws  = (float*)d_ws + 790528;  // 16B-aligned
    float* WT1l = fws;                 // 64*128
    float* WT1r = fws + 8192;          // 64*128
    float* WT2l = fws + 16384;         // 128*128
    float* WT2r = fws + 32768;         // 128*128
    float* h    = fws + 49152;         // 50000*128

    // zero count+cursor (contiguous)
    hipMemsetAsync(count, 0, 100000 * sizeof(int), stream);

    transpose_kernel<<<32, 256, 0, stream>>>(W1l, WT1l, FEAT, 128 * FEAT);
    transpose_kernel<<<32, 256, 0, stream>>>(W1r, WT1r, FEAT, 128 * FEAT);
    transpose_kernel<<<64, 256, 0, stream>>>(W2l, WT2l, HID, 128 * HID);
    transpose_kernel<<<64, 256, 0, stream>>>(W2r, WT2r, HID, 128 * HID);

    hist_kernel<<<(N_EDGES + 255) / 256, 256, 0, stream>>>(dst, count);
    scan1_kernel<<<NB, 256, 0, stream>>>(count, offset, bsum);
    scan2_kernel<<<1, 256, 0, stream>>>(bsum, boff);
    scan3_kernel<<<NB, 256, 0, stream>>>(offset, boff);
    fill_kernel<<<(N_EDGES + 255) / 256, 256, 0, stream>>>(src, dst, offset, cursor, esrc);

    lin1_kernel<<<N_NODES / NT, 256, 0, stream>>>(emb, offset, esrc, WT1l, b1l, WT1r, h);
    lin2_kernel<<<N_NODES / NT, 256, 0, stream>>>(h, offset, esrc, WT2l, b2l, WT2r, out);
}

// Round 3
// 402.043 us; speedup vs baseline: 4.1162x; 1.2328x over previous
//
#include <hip/hip_runtime.h>

#define N_NODES 50000
#define FEAT    64
#define HID     128
#define N_EDGES 640000
#define NT      16      // nodes per lin block
#define NB      196     // scan blocks = ceil(50000/256)
#define IDXCAP  768     // staged edge indices per block (LDS)

// ---------------- weight transpose: out[k*128+o] = in[o*C+k] (R=128 fixed) --
__global__ void transpose_kernel(const float* __restrict__ in,
                                 float* __restrict__ out, int C, int total) {
    int id = blockIdx.x * blockDim.x + threadIdx.x;
    if (id >= total) return;
    int o = id & 127;
    int k = id >> 7;
    out[id] = in[o * C + k];
}

// ---------------- CSR build ------------------------------------------------
__global__ void hist_kernel(const int* __restrict__ dst, int* __restrict__ count) {
    int e = blockIdx.x * blockDim.x + threadIdx.x;
    if (e < N_EDGES) atomicAdd(&count[dst[e]], 1);
}

__global__ __launch_bounds__(256) void scan1_kernel(const int* __restrict__ count,
                                                    int* __restrict__ offset,
                                                    int* __restrict__ bsum) {
    __shared__ int tmp[256];
    int t = threadIdx.x;
    int i = blockIdx.x * 256 + t;
    int v = (i < N_NODES) ? count[i] : 0;
    tmp[t] = v;
    __syncthreads();
    for (int off = 1; off < 256; off <<= 1) {
        int add = (t >= off) ? tmp[t - off] : 0;
        __syncthreads();
        tmp[t] += add;
        __syncthreads();
    }
    if (i < N_NODES) offset[i] = tmp[t] - v;   // exclusive within block
    if (t == 255) bsum[blockIdx.x] = tmp[255];
}

__global__ __launch_bounds__(256) void scan2_kernel(const int* __restrict__ bsum,
                                                    int* __restrict__ boff) {
    __shared__ int tmp[256];
    int t = threadIdx.x;
    int v = (t < NB) ? bsum[t] : 0;
    tmp[t] = v;
    __syncthreads();
    for (int off = 1; off < 256; off <<= 1) {
        int add = (t >= off) ? tmp[t - off] : 0;
        __syncthreads();
        tmp[t] += add;
        __syncthreads();
    }
    if (t < NB) boff[t] = tmp[t] - v;          // exclusive block offsets
}

__global__ void scan3_kernel(int* __restrict__ offset, const int* __restrict__ boff) {
    int i = blockIdx.x * 256 + threadIdx.x;
    if (i < N_NODES) offset[i] += boff[blockIdx.x];
    if (i == 0) offset[N_NODES] = N_EDGES;
}

__global__ void fill_kernel(const int* __restrict__ src, const int* __restrict__ dst,
                            const int* __restrict__ offset, int* __restrict__ cursor,
                            int* __restrict__ esrc) {
    int e = blockIdx.x * blockDim.x + threadIdx.x;
    if (e >= N_EDGES) return;
    int d = dst[e];
    int slot = atomicAdd(&cursor[d], 1);
    esrc[offset[d] + slot] = src[e];
}

// ---------------- layer 1: fused mean-aggregate + dual linear + relu -------
// 256 threads, NT=16 nodes. Gather: 4 f-groups of 64; group w handles nodes
// {w, w+4, w+8, w+12}. Matmul: 8 groups of 32 lanes; thread owns 2 nodes x
// 4 outputs, weights k-major (coalesced float4, L1-hot, reused across nodes).
__global__ __launch_bounds__(256) void lin1_kernel(
        const float* __restrict__ emb, const int* __restrict__ offset,
        const int* __restrict__ esrc,
        const float* __restrict__ WT1l, const float* __restrict__ b1l,
        const float* __restrict__ WT1r,
        float* __restrict__ h) {
    __shared__ float sm[NT][FEAT];
    __shared__ float sx[NT][FEAT];
    __shared__ int   sidx[IDXCAP];
    int t = threadIdx.x;
    int n0 = blockIdx.x * NT;

    int base = offset[n0];
    int tot  = offset[n0 + NT] - base;
    int lim  = (tot < IDXCAP) ? tot : IDXCAP;
    for (int i = t; i < lim; i += 256) sidx[i] = esrc[base + i];
    __syncthreads();

    int w = t >> 6;       // 0..3
    int f = t & 63;
    for (int p = 0; p < 4; ++p) {
        int r = p * 4 + w;
        int n = n0 + r;
        int beg = offset[n], end = offset[n + 1];
        int b = beg - base, e2 = end - base;
        float a0 = 0.f, a1 = 0.f, a2 = 0.f, a3 = 0.f;
        if (e2 <= IDXCAP) {                       // fast path: LDS indices
            int i = b;
            for (; i + 3 < e2; i += 4) {
                int s0 = sidx[i], s1 = sidx[i+1], s2 = sidx[i+2], s3 = sidx[i+3];
                a0 += emb[s0 * FEAT + f]; a1 += emb[s1 * FEAT + f];
                a2 += emb[s2 * FEAT + f]; a3 += emb[s3 * FEAT + f];
            }
            for (; i < e2; ++i) a0 += emb[sidx[i] * FEAT + f];
        } else {                                  // fallback (never in practice)
            for (int i = beg; i < end; ++i) a0 += emb[esrc[i] * FEAT + f];
        }
        float dinv = 1.0f / fmaxf((float)(e2 - b), 1.0f);
        sm[r][f] = ((a0 + a1) + (a2 + a3)) * dinv;
        sx[r][f] = emb[n * FEAT + f];
    }
    __syncthreads();

    int r2 = (t >> 5) << 1;    // node pair base: 0,2,..,14
    int ob = (t & 31) << 2;    // output base 0..124
    float4 bias = *(const float4*)&b1l[ob];
    float4 accA = bias, accB = bias;
    #pragma unroll
    for (int k = 0; k < FEAT; k += 4) {
        float4 mA = *(const float4*)&sm[r2][k];
        float4 mB = *(const float4*)&sm[r2 + 1][k];
        float4 xA = *(const float4*)&sx[r2][k];
        float4 xB = *(const float4*)&sx[r2 + 1][k];
        #pragma unroll
        for (int j = 0; j < 4; ++j) {
            float4 wl = *(const float4*)&WT1l[(k + j) * HID + ob];
            float4 wr = *(const float4*)&WT1r[(k + j) * HID + ob];
            float mAj = (j==0)?mA.x:(j==1)?mA.y:(j==2)?mA.z:mA.w;
            float mBj = (j==0)?mB.x:(j==1)?mB.y:(j==2)?mB.z:mB.w;
            float xAj = (j==0)?xA.x:(j==1)?xA.y:(j==2)?xA.z:xA.w;
            float xBj = (j==0)?xB.x:(j==1)?xB.y:(j==2)?xB.z:xB.w;
            accA.x += mAj*wl.x + xAj*wr.x;  accA.y += mAj*wl.y + xAj*wr.y;
            accA.z += mAj*wl.z + xAj*wr.z;  accA.w += mAj*wl.w + xAj*wr.w;
            accB.x += mBj*wl.x + xBj*wr.x;  accB.y += mBj*wl.y + xBj*wr.y;
            accB.z += mBj*wl.z + xBj*wr.z;  accB.w += mBj*wl.w + xBj*wr.w;
        }
    }
    float4 oA, oB;
    oA.x = fmaxf(accA.x, 0.f); oA.y = fmaxf(accA.y, 0.f);
    oA.z = fmaxf(accA.z, 0.f); oA.w = fmaxf(accA.w, 0.f);
    oB.x = fmaxf(accB.x, 0.f); oB.y = fmaxf(accB.y, 0.f);
    oB.z = fmaxf(accB.z, 0.f); oB.w = fmaxf(accB.w, 0.f);
    *(float4*)&h[(n0 + r2) * HID + ob] = oA;
    *(float4*)&h[(n0 + r2 + 1) * HID + ob] = oB;
}

// ---------------- layer 2: fused mean-aggregate + dual linear --------------
__global__ __launch_bounds__(256) void lin2_kernel(
        const float* __restrict__ h, const int* __restrict__ offset,
        const int* __restrict__ esrc,
        const float* __restrict__ WT2l, const float* __restrict__ b2l,
        const float* __restrict__ WT2r,
        float* __restrict__ out) {
    __shared__ float sm[NT][HID];
    __shared__ float sx[NT][HID];
    __shared__ int   sidx[IDXCAP];
    int t = threadIdx.x;
    int n0 = blockIdx.x * NT;

    int base = offset[n0];
    int tot  = offset[n0 + NT] - base;
    int lim  = (tot < IDXCAP) ? tot : IDXCAP;
    for (int i = t; i < lim; i += 256) sidx[i] = esrc[base + i];
    __syncthreads();

    int g = t >> 7;        // 0..1 (128-lane group)
    int f = t & 127;
    for (int p = 0; p < 8; ++p) {
        int r = p * 2 + g;
        int n = n0 + r;
        int beg = offset[n], end = offset[n + 1];
        int b = beg - base, e2 = end - base;
        float a0 = 0.f, a1 = 0.f, a2 = 0.f, a3 = 0.f;
        if (e2 <= IDXCAP) {
            int i = b;
            for (; i + 3 < e2; i += 4) {
                int s0 = sidx[i], s1 = sidx[i+1], s2 = sidx[i+2], s3 = sidx[i+3];
                a0 += h[s0 * HID + f]; a1 += h[s1 * HID + f];
                a2 += h[s2 * HID + f]; a3 += h[s3 * HID + f];
            }
            for (; i < e2; ++i) a0 += h[sidx[i] * HID + f];
        } else {
            for (int i = beg; i < end; ++i) a0 += h[esrc[i] * HID + f];
        }
        float dinv = 1.0f / fmaxf((float)(e2 - b), 1.0f);
        sm[r][f] = ((a0 + a1) + (a2 + a3)) * dinv;
        sx[r][f] = h[n * HID + f];
    }
    __syncthreads();

    int r2 = (t >> 5) << 1;
    int ob = (t & 31) << 2;
    float4 bias = *(const float4*)&b2l[ob];
    float4 accA = bias, accB = bias;
    #pragma unroll 8
    for (int k = 0; k < HID; k += 4) {
        float4 mA = *(const float4*)&sm[r2][k];
        float4 mB = *(const float4*)&sm[r2 + 1][k];
        float4 xA = *(const float4*)&sx[r2][k];
        float4 xB = *(const float4*)&sx[r2 + 1][k];
        #pragma unroll
        for (int j = 0; j < 4; ++j) {
            float4 wl = *(const float4*)&WT2l[(k + j) * HID + ob];
            float4 wr = *(const float4*)&WT2r[(k + j) * HID + ob];
            float mAj = (j==0)?mA.x:(j==1)?mA.y:(j==2)?mA.z:mA.w;
            float mBj = (j==0)?mB.x:(j==1)?mB.y:(j==2)?mB.z:mB.w;
            float xAj = (j==0)?xA.x:(j==1)?xA.y:(j==2)?xA.z:xA.w;
            float xBj = (j==0)?xB.x:(j==1)?xB.y:(j==2)?xB.z:xB.w;
            accA.x += mAj*wl.x + xAj*wr.x;  accA.y += mAj*wl.y + xAj*wr.y;
            accA.z += mAj*wl.z + xAj*wr.z;  accA.w += mAj*wl.w + xAj*wr.w;
            accB.x += mBj*wl.x + xBj*wr.x;  accB.y += mBj*wl.y + xBj*wr.y;
            accB.z += mBj*wl.z + xBj*wr.z;  accB.w += mBj*wl.w + xBj*wr.w;
        }
    }
    *(float4*)&out[(n0 + r2) * HID + ob] = accA;
    *(float4*)&out[(n0 + r2 + 1) * HID + ob] = accB;
}

extern "C" void kernel_launch(void* const* d_in, const int* in_sizes, int n_in,
                              void* d_out, int out_size, void* d_ws, size_t ws_size,
                              hipStream_t stream) {
    const int*   edge_index = (const int*)d_in[0];   // [2, E]
    const float* emb        = (const float*)d_in[1]; // [N, 64]
    const float* W1l        = (const float*)d_in[2]; // [128, 64]
    const float* b1l        = (const float*)d_in[3]; // [128]
    const float* W1r        = (const float*)d_in[4]; // [128, 64]
    const float* W2l        = (const float*)d_in[5]; // [128, 128]
    const float* b2l        = (const float*)d_in[6]; // [128]
    const float* W2r        = (const float*)d_in[7]; // [128, 128]
    float* out = (float*)d_out;

    const int* src = edge_index;
    const int* dst = edge_index + N_EDGES;

    // ---- ws layout (ints then 16B-aligned floats), ~29 MB total ----
    int* iws    = (int*)d_ws;
    int* offset = iws;                 // 50001
    int* count  = iws + 50004;         // 50000
    int* cursor = iws + 100004;        // 50000 (contiguous with count)
    int* bsum   = iws + 150004;        // 256
    int* boff   = iws + 150260;        // 256
    int* esrc   = iws + 150516;        // 640000  (ends 790516)
    float* fws  = (float*)d_ws + 790528;  // 16B-aligned
    float* WT1l = fws;                 // 64*128
    float* WT1r = fws + 8192;          // 64*128
    float* WT2l = fws + 16384;         // 128*128
    float* WT2r = fws + 32768;         // 128*128
    float* h    = fws + 49152;         // 50000*128

    // zero count+cursor (contiguous)
    hipMemsetAsync(count, 0, 100000 * sizeof(int), stream);

    transpose_kernel<<<32, 256, 0, stream>>>(W1l, WT1l, FEAT, 128 * FEAT);
    transpose_kernel<<<32, 256, 0, stream>>>(W1r, WT1r, FEAT, 128 * FEAT);
    transpose_kernel<<<64, 256, 0, stream>>>(W2l, WT2l, HID, 128 * HID);
    transpose_kernel<<<64, 256, 0, stream>>>(W2r, WT2r, HID, 128 * HID);

    hist_kernel<<<(N_EDGES + 255) / 256, 256, 0, stream>>>(dst, count);
    scan1_kernel<<<NB, 256, 0, stream>>>(count, offset, bsum);
    scan2_kernel<<<1, 256, 0, stream>>>(bsum, boff);
    scan3_kernel<<<NB, 256, 0, stream>>>(offset, boff);
    fill_kernel<<<(N_EDGES + 255) / 256, 256, 0, stream>>>(src, dst, offset, cursor, esrc);

    lin1_kernel<<<N_NODES / NT, 256, 0, stream>>>(emb, offset, esrc, WT1l, b1l, WT1r, h);
    lin2_kernel<<<N_NODES / NT, 256, 0, stream>>>(h, offset, esrc, WT2l, b2l, WT2r, out);
}

// Round 4
// 280.382 us; speedup vs baseline: 5.9023x; 1.4339x over previous
//
#include <hip/hip_runtime.h>

#define N_NODES 50000
#define FEAT    64
#define HID     128
#define N_EDGES 640000
#define NB      196     // scan blocks = ceil(50000/256)

typedef __attribute__((ext_vector_type(8))) short bf16x8;
typedef __attribute__((ext_vector_type(4))) float f32x4;

static __device__ __forceinline__ unsigned short f2bf(float f) {
    unsigned u = __float_as_uint(f);
    u = u + 0x7fffu + ((u >> 16) & 1u);          // RNE
    return (unsigned short)(u >> 16);
}
static __device__ __forceinline__ float bf2f(unsigned short s) {
    return __uint_as_float(((unsigned)s) << 16);
}

// ---------------- fp32 -> bf16 conversions ---------------------------------
__global__ void cvt_emb_kernel(const float* __restrict__ in,
                               unsigned short* __restrict__ out) {
    int id = blockIdx.x * blockDim.x + threadIdx.x;
    if (id < N_NODES * FEAT) out[id] = f2bf(in[id]);
}

// weights: [0,8192)=W1l [8192,16384)=W1r [16384,32768)=W2l [32768,49152)=W2r
__global__ void cvt_w_kernel(const float* __restrict__ W1l, const float* __restrict__ W1r,
                             const float* __restrict__ W2l, const float* __restrict__ W2r,
                             unsigned short* __restrict__ out) {
    int id = blockIdx.x * blockDim.x + threadIdx.x;
    if (id >= 49152) return;
    float v;
    if (id < 8192)       v = W1l[id];
    else if (id < 16384) v = W1r[id - 8192];
    else if (id < 32768) v = W2l[id - 16384];
    else                 v = W2r[id - 32768];
    out[id] = f2bf(v);
}

// ---------------- CSR build ------------------------------------------------
__global__ void hist_kernel(const int* __restrict__ dst, int* __restrict__ count) {
    int e = blockIdx.x * blockDim.x + threadIdx.x;
    if (e < N_EDGES) atomicAdd(&count[dst[e]], 1);
}

__global__ __launch_bounds__(256) void scan1_kernel(const int* __restrict__ count,
                                                    int* __restrict__ offset,
                                                    int* __restrict__ bsum) {
    __shared__ int tmp[256];
    int t = threadIdx.x;
    int i = blockIdx.x * 256 + t;
    int v = (i < N_NODES) ? count[i] : 0;
    tmp[t] = v;
    __syncthreads();
    for (int off = 1; off < 256; off <<= 1) {
        int add = (t >= off) ? tmp[t - off] : 0;
        __syncthreads();
        tmp[t] += add;
        __syncthreads();
    }
    if (i < N_NODES) offset[i] = tmp[t] - v;
    if (t == 255) bsum[blockIdx.x] = tmp[255];
}

__global__ __launch_bounds__(256) void scan2_kernel(const int* __restrict__ bsum,
                                                    int* __restrict__ boff) {
    __shared__ int tmp[256];
    int t = threadIdx.x;
    int v = (t < NB) ? bsum[t] : 0;
    tmp[t] = v;
    __syncthreads();
    for (int off = 1; off < 256; off <<= 1) {
        int add = (t >= off) ? tmp[t - off] : 0;
        __syncthreads();
        tmp[t] += add;
        __syncthreads();
    }
    if (t < NB) boff[t] = tmp[t] - v;
}

__global__ void scan3_kernel(int* __restrict__ offset, const int* __restrict__ boff) {
    int i = blockIdx.x * 256 + threadIdx.x;
    if (i < N_NODES) offset[i] += boff[blockIdx.x];
    if (i == 0) offset[N_NODES] = N_EDGES;
}

__global__ void fill_kernel(const int* __restrict__ src, const int* __restrict__ dst,
                            const int* __restrict__ offset, int* __restrict__ cursor,
                            int* __restrict__ esrc) {
    int e = blockIdx.x * blockDim.x + threadIdx.x;
    if (e >= N_EDGES) return;
    int d = dst[e];
    int slot = atomicAdd(&cursor[d], 1);
    esrc[offset[d] + slot] = src[e];
}

// ---------------- gather 1: mean of emb_bf16 rows (64 feats) ---------------
// One wave per node. lane = feature. Wave-uniform index loads (s_load),
// 8 independent row loads in flight.
__global__ __launch_bounds__(256) void gather1_kernel(
        const unsigned short* __restrict__ embb, const int* __restrict__ offset,
        const int* __restrict__ esrc, unsigned short* __restrict__ mean1) {
    int n = blockIdx.x * 4 + (threadIdx.x >> 6);
    int lane = threadIdx.x & 63;
    int beg = offset[n], end = offset[n + 1];
    float a0=0.f,a1=0.f,a2=0.f,a3=0.f,a4=0.f,a5=0.f,a6=0.f,a7=0.f;
    int i = beg;
    for (; i + 8 <= end; i += 8) {
        int s0=esrc[i],s1=esrc[i+1],s2=esrc[i+2],s3=esrc[i+3];
        int s4=esrc[i+4],s5=esrc[i+5],s6=esrc[i+6],s7=esrc[i+7];
        a0 += bf2f(embb[s0*FEAT+lane]); a1 += bf2f(embb[s1*FEAT+lane]);
        a2 += bf2f(embb[s2*FEAT+lane]); a3 += bf2f(embb[s3*FEAT+lane]);
        a4 += bf2f(embb[s4*FEAT+lane]); a5 += bf2f(embb[s5*FEAT+lane]);
        a6 += bf2f(embb[s6*FEAT+lane]); a7 += bf2f(embb[s7*FEAT+lane]);
    }
    for (; i < end; ++i) a0 += bf2f(embb[esrc[i]*FEAT+lane]);
    float sum = ((a0+a1)+(a2+a3)) + ((a4+a5)+(a6+a7));
    float dinv = 1.0f / fmaxf((float)(end - beg), 1.0f);
    mean1[n*FEAT + lane] = f2bf(sum * dinv);
}

// ---------------- gather 2: mean of h_bf16 rows (128 feats) ----------------
// One wave per node. lane covers 2 features via packed uint (bf16x2).
__global__ __launch_bounds__(256) void gather2_kernel(
        const unsigned int* __restrict__ hb, const int* __restrict__ offset,
        const int* __restrict__ esrc, unsigned int* __restrict__ mean2) {
    int n = blockIdx.x * 4 + (threadIdx.x >> 6);
    int lane = threadIdx.x & 63;
    int beg = offset[n], end = offset[n + 1];
    float lo0=0.f,lo1=0.f,lo2=0.f,lo3=0.f,lo4=0.f,lo5=0.f,lo6=0.f,lo7=0.f;
    float hi0=0.f,hi1=0.f,hi2=0.f,hi3=0.f,hi4=0.f,hi5=0.f,hi6=0.f,hi7=0.f;
    int i = beg;
    for (; i + 8 <= end; i += 8) {
        int s0=esrc[i],s1=esrc[i+1],s2=esrc[i+2],s3=esrc[i+3];
        int s4=esrc[i+4],s5=esrc[i+5],s6=esrc[i+6],s7=esrc[i+7];
        unsigned u0=hb[s0*64+lane], u1=hb[s1*64+lane], u2=hb[s2*64+lane], u3=hb[s3*64+lane];
        unsigned u4=hb[s4*64+lane], u5=hb[s5*64+lane], u6=hb[s6*64+lane], u7=hb[s7*64+lane];
        lo0 += __uint_as_float(u0<<16); hi0 += __uint_as_float(u0 & 0xffff0000u);
        lo1 += __uint_as_float(u1<<16); hi1 += __uint_as_float(u1 & 0xffff0000u);
        lo2 += __uint_as_float(u2<<16); hi2 += __uint_as_float(u2 & 0xffff0000u);
        lo3 += __uint_as_float(u3<<16); hi3 += __uint_as_float(u3 & 0xffff0000u);
        lo4 += __uint_as_float(u4<<16); hi4 += __uint_as_float(u4 & 0xffff0000u);
        lo5 += __uint_as_float(u5<<16); hi5 += __uint_as_float(u5 & 0xffff0000u);
        lo6 += __uint_as_float(u6<<16); hi6 += __uint_as_float(u6 & 0xffff0000u);
        lo7 += __uint_as_float(u7<<16); hi7 += __uint_as_float(u7 & 0xffff0000u);
    }
    for (; i < end; ++i) {
        unsigned u = hb[esrc[i]*64 + lane];
        lo0 += __uint_as_float(u<<16); hi0 += __uint_as_float(u & 0xffff0000u);
    }
    float lo = ((lo0+lo1)+(lo2+lo3)) + ((lo4+lo5)+(lo6+lo7));
    float hi = ((hi0+hi1)+(hi2+hi3)) + ((hi4+hi5)+(hi6+hi7));
    float dinv = 1.0f / fmaxf((float)(end - beg), 1.0f);
    unsigned out = ((unsigned)f2bf(hi * dinv) << 16) | (unsigned)f2bf(lo * dinv);
    mean2[n*64 + lane] = out;
}

// ---------------- GEMM layer 1: h = relu(mean1@W1l^T + b1l + emb@W1r^T) ----
// bf16 MFMA 16x16x32. One wave per 16-row M-tile, all 8 N-tiles (N=128).
// A-frag: lane holds A[m=lane&15][k=quad*8+j]. B-frag: lane holds
// B[n=lane&15][k=quad*8+j] -> native row-major W[n][k]. C/D: col=lane&15,
// row=quad*4+reg (verified m89/m91).
__global__ __launch_bounds__(256) void gemm1_kernel(
        const short* __restrict__ mean1, const short* __restrict__ embb,
        const short* __restrict__ Wl, const short* __restrict__ Wr,
        const float* __restrict__ bias, unsigned short* __restrict__ hout) {
    int wid = blockIdx.x * 4 + (threadIdx.x >> 6);
    if (wid >= N_NODES / 16) return;
    int lane = threadIdx.x & 63;
    int col = lane & 15, quad = lane >> 4;
    int m0 = wid * 16;
    f32x4 acc[8];
    #pragma unroll
    for (int nt = 0; nt < 8; ++nt) acc[nt] = (f32x4){0.f,0.f,0.f,0.f};

    #pragma unroll
    for (int kb = 0; kb < FEAT; kb += 32) {
        bf16x8 a = *(const bf16x8*)(mean1 + (m0 + col) * FEAT + kb + quad * 8);
        #pragma unroll
        for (int nt = 0; nt < 8; ++nt) {
            bf16x8 b = *(const bf16x8*)(Wl + (nt * 16 + col) * FEAT + kb + quad * 8);
            acc[nt] = __builtin_amdgcn_mfma_f32_16x16x32_bf16(a, b, acc[nt], 0, 0, 0);
        }
    }
    #pragma unroll
    for (int kb = 0; kb < FEAT; kb += 32) {
        bf16x8 a = *(const bf16x8*)(embb + (m0 + col) * FEAT + kb + quad * 8);
        #pragma unroll
        for (int nt = 0; nt < 8; ++nt) {
            bf16x8 b = *(const bf16x8*)(Wr + (nt * 16 + col) * FEAT + kb + quad * 8);
            acc[nt] = __builtin_amdgcn_mfma_f32_16x16x32_bf16(a, b, acc[nt], 0, 0, 0);
        }
    }
    #pragma unroll
    for (int nt = 0; nt < 8; ++nt) {
        float bv = bias[nt * 16 + col];
        #pragma unroll
        for (int r = 0; r < 4; ++r) {
            float v = acc[nt][r] + bv;
            v = fmaxf(v, 0.f);
            hout[(m0 + quad * 4 + r) * HID + nt * 16 + col] = f2bf(v);
        }
    }
}

// ---------------- GEMM layer 2: out = mean2@W2l^T + b2l + h@W2r^T ----------
__global__ __launch_bounds__(256) void gemm2_kernel(
        const short* __restrict__ mean2, const short* __restrict__ hbf,
        const short* __restrict__ Wl, const short* __restrict__ Wr,
        const float* __restrict__ bias, float* __restrict__ out) {
    int wid = blockIdx.x * 4 + (threadIdx.x >> 6);
    if (wid >= N_NODES / 16) return;
    int lane = threadIdx.x & 63;
    int col = lane & 15, quad = lane >> 4;
    int m0 = wid * 16;
    f32x4 acc[8];
    #pragma unroll
    for (int nt = 0; nt < 8; ++nt) acc[nt] = (f32x4){0.f,0.f,0.f,0.f};

    #pragma unroll
    for (int kb = 0; kb < HID; kb += 32) {
        bf16x8 a = *(const bf16x8*)(mean2 + (m0 + col) * HID + kb + quad * 8);
        #pragma unroll
        for (int nt = 0; nt < 8; ++nt) {
            bf16x8 b = *(const bf16x8*)(Wl + (nt * 16 + col) * HID + kb + quad * 8);
            acc[nt] = __builtin_amdgcn_mfma_f32_16x16x32_bf16(a, b, acc[nt], 0, 0, 0);
        }
    }
    #pragma unroll
    for (int kb = 0; kb < HID; kb += 32) {
        bf16x8 a = *(const bf16x8*)(hbf + (m0 + col) * HID + kb + quad * 8);
        #pragma unroll
        for (int nt = 0; nt < 8; ++nt) {
            bf16x8 b = *(const bf16x8*)(Wr + (nt * 16 + col) * HID + kb + quad * 8);
            acc[nt] = __builtin_amdgcn_mfma_f32_16x16x32_bf16(a, b, acc[nt], 0, 0, 0);
        }
    }
    #pragma unroll
    for (int nt = 0; nt < 8; ++nt) {
        float bv = bias[nt * 16 + col];
        #pragma unroll
        for (int r = 0; r < 4; ++r) {
            out[(m0 + quad * 4 + r) * HID + nt * 16 + col] = acc[nt][r] + bv;
        }
    }
}

extern "C" void kernel_launch(void* const* d_in, const int* in_sizes, int n_in,
                              void* d_out, int out_size, void* d_ws, size_t ws_size,
                              hipStream_t stream) {
    const int*   edge_index = (const int*)d_in[0];   // [2, E]
    const float* emb        = (const float*)d_in[1]; // [N, 64]
    const float* W1l        = (const float*)d_in[2]; // [128, 64]
    const float* b1l        = (const float*)d_in[3]; // [128]
    const float* W1r        = (const float*)d_in[4]; // [128, 64]
    const float* W2l        = (const float*)d_in[5]; // [128, 128]
    const float* b2l        = (const float*)d_in[6]; // [128]
    const float* W2r        = (const float*)d_in[7]; // [128, 128]
    float* out = (float*)d_out;

    const int* src = edge_index;
    const int* dst = edge_index + N_EDGES;

    // ---- ws layout, int-indexed (all offsets 16B-aligned), ~42 MB ----
    int* iws    = (int*)d_ws;
    int* offset = iws;                        // 50001 (+pad 3)
    int* count  = iws + 50004;                // 50000
    int* cursor = iws + 100004;               // 50000 (contiguous with count)
    int* bsum   = iws + 150004;               // 256
    int* boff   = iws + 150260;               // 256
    int* esrc   = iws + 150516;               // 640000 -> 790516
    unsigned short* W1l_bf = (unsigned short*)(iws + 790516);   // 8192 bf16
    unsigned short* W1r_bf = (unsigned short*)(iws + 794612);   // 8192
    unsigned short* W2l_bf = (unsigned short*)(iws + 798708);   // 16384
    unsigned short* W2r_bf = (unsigned short*)(iws + 806900);   // 16384
    unsigned short* Wbf    = W1l_bf;                             // contiguous 49152
    unsigned short* emb_bf = (unsigned short*)(iws + 815092);   // 3.2M bf16
    unsigned short* mean1  = (unsigned short*)(iws + 2415092);  // 3.2M bf16
    unsigned short* hbf    = (unsigned short*)(iws + 4015092);  // 6.4M bf16
    unsigned short* mean2  = (unsigned short*)(iws + 7215092);  // 6.4M bf16

    hipMemsetAsync(count, 0, 100000 * sizeof(int), stream);

    cvt_emb_kernel<<<(N_NODES * FEAT + 255) / 256, 256, 0, stream>>>(emb, emb_bf);
    cvt_w_kernel<<<192, 256, 0, stream>>>(W1l, W1r, W2l, W2r, Wbf);

    hist_kernel<<<(N_EDGES + 255) / 256, 256, 0, stream>>>(dst, count);
    scan1_kernel<<<NB, 256, 0, stream>>>(count, offset, bsum);
    scan2_kernel<<<1, 256, 0, stream>>>(bsum, boff);
    scan3_kernel<<<NB, 256, 0, stream>>>(offset, boff);
    fill_kernel<<<(N_EDGES + 255) / 256, 256, 0, stream>>>(src, dst, offset, cursor, esrc);

    gather1_kernel<<<N_NODES / 4, 256, 0, stream>>>(emb_bf, offset, esrc, mean1);
    gemm1_kernel<<<(N_NODES / 16 + 3) / 4, 256, 0, stream>>>(
        (const short*)mean1, (const short*)emb_bf,
        (const short*)W1l_bf, (const short*)W1r_bf, b1l, hbf);
    gather2_kernel<<<N_NODES / 4, 256, 0, stream>>>(
        (const unsigned int*)hbf, offset, esrc, (unsigned int*)mean2);
    gemm2_kernel<<<(N_NODES / 16 + 3) / 4, 256, 0, stream>>>(
        (const short*)mean2, (const short*)hbf,
        (const short*)W2l_bf, (const short*)W2r_bf, b2l, out);
}

// Round 5
// 264.318 us; speedup vs baseline: 6.2610x; 1.0608x over previous
//
#include <hip/hip_runtime.h>

#define N_NODES 50000
#define FEAT    64
#define HID     128
#define N_EDGES 640000
#define NB      196     // scan blocks = ceil(50000/256)
#define GCAP    64      // per-node staged index capacity (deg>64 -> global fallback)

typedef __attribute__((ext_vector_type(8))) short bf16x8;
typedef __attribute__((ext_vector_type(4))) float f32x4;

static __device__ __forceinline__ unsigned short f2bf(float f) {
    unsigned u = __float_as_uint(f);
    u = u + 0x7fffu + ((u >> 16) & 1u);          // RNE
    return (unsigned short)(u >> 16);
}

// ---------------- fp32 -> bf16 conversions (emb + all weights) -------------
// layout in Wbf: [0,8192)=W1l [8192,16384)=W1r [16384,32768)=W2l [32768,49152)=W2r
__global__ void cvt_all_kernel(const float* __restrict__ emb,
                               const float* __restrict__ W1l, const float* __restrict__ W1r,
                               const float* __restrict__ W2l, const float* __restrict__ W2r,
                               unsigned short* __restrict__ emb_bf,
                               unsigned short* __restrict__ Wbf) {
    int id = blockIdx.x * blockDim.x + threadIdx.x;
    if (id < N_NODES * FEAT) {
        emb_bf[id] = f2bf(emb[id]);
    }
    int w = id - N_NODES * FEAT;
    if (w >= 0 && w < 49152) {
        float v;
        if (w < 8192)       v = W1l[w];
        else if (w < 16384) v = W1r[w - 8192];
        else if (w < 32768) v = W2l[w - 16384];
        else                v = W2r[w - 32768];
        Wbf[w] = f2bf(v);
    }
}

// ---------------- CSR build ------------------------------------------------
__global__ void hist_kernel(const int* __restrict__ dst, int* __restrict__ count) {
    int e = blockIdx.x * blockDim.x + threadIdx.x;
    if (e < N_EDGES) atomicAdd(&count[dst[e]], 1);
}

// block-scan of count -> per-block-exclusive offset, block sums, + degree hist
__global__ __launch_bounds__(256) void scan1_kernel(const int* __restrict__ count,
                                                    int* __restrict__ offset,
                                                    int* __restrict__ bsum,
                                                    int* __restrict__ dhist) {
    __shared__ int tmp[256];
    __shared__ int lh[64];
    int t = threadIdx.x;
    int i = blockIdx.x * 256 + t;
    if (t < 64) lh[t] = 0;
    int v = (i < N_NODES) ? count[i] : 0;
    tmp[t] = v;
    __syncthreads();
    if (i < N_NODES) atomicAdd(&lh[v < 63 ? v : 63], 1);
    for (int off = 1; off < 256; off <<= 1) {
        int add = (t >= off) ? tmp[t - off] : 0;
        __syncthreads();
        tmp[t] += add;
        __syncthreads();
    }
    if (i < N_NODES) offset[i] = tmp[t] - v;
    if (t == 255) bsum[blockIdx.x] = tmp[255];
    if (t < 64 && lh[t] > 0) atomicAdd(&dhist[t], lh[t]);
}

// block 0: exclusive-scan bsum[NB] -> boff; block 1: dhist[64] -> dstart
__global__ __launch_bounds__(256) void scan2_kernel(const int* __restrict__ bsum,
                                                    int* __restrict__ boff,
                                                    const int* __restrict__ dhist,
                                                    int* __restrict__ dstart) {
    __shared__ int tmp[256];
    int t = threadIdx.x;
    const int* in  = (blockIdx.x == 0) ? bsum : dhist;
    int*       out = (blockIdx.x == 0) ? boff : dstart;
    int cnt        = (blockIdx.x == 0) ? NB   : 64;
    int v = (t < cnt) ? in[t] : 0;
    tmp[t] = v;
    __syncthreads();
    for (int off = 1; off < 256; off <<= 1) {
        int add = (t >= off) ? tmp[t - off] : 0;
        __syncthreads();
        tmp[t] += add;
        __syncthreads();
    }
    if (t < cnt) out[t] = tmp[t] - v;
}

__global__ void scan3_kernel(int* __restrict__ offset, const int* __restrict__ boff) {
    int i = blockIdx.x * 256 + threadIdx.x;
    if (i < N_NODES) offset[i] += boff[blockIdx.x];
    if (i == 0) offset[N_NODES] = N_EDGES;
}

__global__ void fill_kernel(const int* __restrict__ src, const int* __restrict__ dst,
                            const int* __restrict__ offset, int* __restrict__ cursor,
                            int* __restrict__ esrc) {
    int e = blockIdx.x * blockDim.x + threadIdx.x;
    if (e >= N_EDGES) return;
    int d = dst[e];
    int slot = atomicAdd(&cursor[d], 1);
    esrc[offset[d] + slot] = src[e];
}

// counting-sort nodes by degree: perm[pos] = node, pos grouped by degree.
__global__ __launch_bounds__(256) void permute_kernel(
        const int* __restrict__ count, const int* __restrict__ dstart,
        int* __restrict__ dcur, int* __restrict__ perm) {
    __shared__ int lbin[64];
    __shared__ int lbase[64];
    int t = threadIdx.x;
    int i = blockIdx.x * 256 + t;
    if (t < 64) lbin[t] = 0;
    __syncthreads();
    int d = 0, slot = 0;
    if (i < N_NODES) {
        int c = count[i];
        d = c < 63 ? c : 63;
        slot = atomicAdd(&lbin[d], 1);
    }
    __syncthreads();
    if (t < 64 && lbin[t] > 0) lbase[t] = atomicAdd(&dcur[t], lbin[t]);
    __syncthreads();
    if (i < N_NODES) perm[dstart[d] + lbase[d] + slot] = i;
}

// ---------------- gather 1: mean of emb_bf16 rows (64 feats = 128 B) -------
// 256 threads = 4 waves, 8 nodes/wave (8 lanes x float4 per row).
// Degree-sorted perm order -> near-uniform trip counts within a wave.
__global__ __launch_bounds__(256) void gather1_kernel(
        const float4* __restrict__ emb4, const int* __restrict__ offset,
        const int* __restrict__ esrc, const int* __restrict__ perm,
        uint4* __restrict__ mean1_u4) {
    __shared__ int sidx[4][8][GCAP];
    int t = threadIdx.x, wave = t >> 6, lane = t & 63;
    int sub = lane >> 3, fl = lane & 7;
    int widx = blockIdx.x * 32 + wave * 8 + sub;
    bool valid = widx < N_NODES;
    int n = 0, beg = 0, deg = 0;
    if (valid) { n = perm[widx]; beg = offset[n]; deg = offset[n + 1] - beg; }
    bool fast = deg <= GCAP;
    if (valid && fast) {
        for (int j = fl; j < deg; j += 8) sidx[wave][sub][j] = esrc[beg + j];
    }
    __syncthreads();
    float a[8] = {0.f,0.f,0.f,0.f,0.f,0.f,0.f,0.f};
    if (valid) {
        if (fast) {
            int i = 0;
            for (; i + 4 <= deg; i += 4) {
                int s0 = sidx[wave][sub][i+0], s1 = sidx[wave][sub][i+1];
                int s2 = sidx[wave][sub][i+2], s3 = sidx[wave][sub][i+3];
                float4 v0 = emb4[s0*8+fl], v1 = emb4[s1*8+fl];
                float4 v2 = emb4[s2*8+fl], v3 = emb4[s3*8+fl];
                #define ACC1(v) { \
                    unsigned ux=__float_as_uint((v).x),uy=__float_as_uint((v).y); \
                    unsigned uz=__float_as_uint((v).z),uw=__float_as_uint((v).w); \
                    a[0]+=__uint_as_float(ux<<16); a[1]+=__uint_as_float(ux&0xffff0000u); \
                    a[2]+=__uint_as_float(uy<<16); a[3]+=__uint_as_float(uy&0xffff0000u); \
                    a[4]+=__uint_as_float(uz<<16); a[5]+=__uint_as_float(uz&0xffff0000u); \
                    a[6]+=__uint_as_float(uw<<16); a[7]+=__uint_as_float(uw&0xffff0000u); }
                ACC1(v0) ACC1(v1) ACC1(v2) ACC1(v3)
            }
            for (; i < deg; ++i) { float4 v = emb4[sidx[wave][sub][i]*8+fl]; ACC1(v) }
        } else {
            for (int i = 0; i < deg; ++i) { float4 v = emb4[esrc[beg+i]*8+fl]; ACC1(v) }
        }
        float dinv = 1.0f / fmaxf((float)deg, 1.0f);
        uint4 o;
        o.x = ((unsigned)f2bf(a[1]*dinv) << 16) | (unsigned)f2bf(a[0]*dinv);
        o.y = ((unsigned)f2bf(a[3]*dinv) << 16) | (unsigned)f2bf(a[2]*dinv);
        o.z = ((unsigned)f2bf(a[5]*dinv) << 16) | (unsigned)f2bf(a[4]*dinv);
        o.w = ((unsigned)f2bf(a[7]*dinv) << 16) | (unsigned)f2bf(a[6]*dinv);
        mean1_u4[n*8 + fl] = o;
    }
}

// ---------------- gather 2: mean of h_bf16 rows (128 feats = 256 B) --------
// 4 nodes/wave (16 lanes x float4 per row).
__global__ __launch_bounds__(256) void gather2_kernel(
        const float4* __restrict__ h4, const int* __restrict__ offset,
        const int* __restrict__ esrc, const int* __restrict__ perm,
        uint4* __restrict__ mean2_u4) {
    __shared__ int sidx[4][4][GCAP];
    int t = threadIdx.x, wave = t >> 6, lane = t & 63;
    int sub = lane >> 4, fl = lane & 15;
    int widx = blockIdx.x * 16 + wave * 4 + sub;
    bool valid = widx < N_NODES;
    int n = 0, beg = 0, deg = 0;
    if (valid) { n = perm[widx]; beg = offset[n]; deg = offset[n + 1] - beg; }
    bool fast = deg <= GCAP;
    if (valid && fast) {
        for (int j = fl; j < deg; j += 16) sidx[wave][sub][j] = esrc[beg + j];
    }
    __syncthreads();
    float a[8] = {0.f,0.f,0.f,0.f,0.f,0.f,0.f,0.f};
    if (valid) {
        if (fast) {
            int i = 0;
            for (; i + 4 <= deg; i += 4) {
                int s0 = sidx[wave][sub][i+0], s1 = sidx[wave][sub][i+1];
                int s2 = sidx[wave][sub][i+2], s3 = sidx[wave][sub][i+3];
                float4 v0 = h4[s0*16+fl], v1 = h4[s1*16+fl];
                float4 v2 = h4[s2*16+fl], v3 = h4[s3*16+fl];
                ACC1(v0) ACC1(v1) ACC1(v2) ACC1(v3)
            }
            for (; i < deg; ++i) { float4 v = h4[sidx[wave][sub][i]*16+fl]; ACC1(v) }
        } else {
            for (int i = 0; i < deg; ++i) { float4 v = h4[esrc[beg+i]*16+fl]; ACC1(v) }
        }
        float dinv = 1.0f / fmaxf((float)deg, 1.0f);
        uint4 o;
        o.x = ((unsigned)f2bf(a[1]*dinv) << 16) | (unsigned)f2bf(a[0]*dinv);
        o.y = ((unsigned)f2bf(a[3]*dinv) << 16) | (unsigned)f2bf(a[2]*dinv);
        o.z = ((unsigned)f2bf(a[5]*dinv) << 16) | (unsigned)f2bf(a[4]*dinv);
        o.w = ((unsigned)f2bf(a[7]*dinv) << 16) | (unsigned)f2bf(a[6]*dinv);
        mean2_u4[n*16 + fl] = o;
    }
}

// ---------------- GEMM layer 1: h = relu(mean1@W1l^T + b1l + emb@W1r^T) ----
// bf16 MFMA 16x16x32; C/D: col=lane&15, row=quad*4+reg (verified m89/m91).
__global__ __launch_bounds__(256) void gemm1_kernel(
        const short* __restrict__ mean1, const short* __restrict__ embb,
        const short* __restrict__ Wl, const short* __restrict__ Wr,
        const float* __restrict__ bias, unsigned short* __restrict__ hout) {
    int wid = blockIdx.x * 4 + (threadIdx.x >> 6);
    if (wid >= N_NODES / 16) return;
    int lane = threadIdx.x & 63;
    int col = lane & 15, quad = lane >> 4;
    int m0 = wid * 16;
    f32x4 acc[8];
    #pragma unroll
    for (int nt = 0; nt < 8; ++nt) acc[nt] = (f32x4){0.f,0.f,0.f,0.f};
    #pragma unroll
    for (int kb = 0; kb < FEAT; kb += 32) {
        bf16x8 a = *(const bf16x8*)(mean1 + (m0 + col) * FEAT + kb + quad * 8);
        #pragma unroll
        for (int nt = 0; nt < 8; ++nt) {
            bf16x8 b = *(const bf16x8*)(Wl + (nt * 16 + col) * FEAT + kb + quad * 8);
            acc[nt] = __builtin_amdgcn_mfma_f32_16x16x32_bf16(a, b, acc[nt], 0, 0, 0);
        }
    }
    #pragma unroll
    for (int kb = 0; kb < FEAT; kb += 32) {
        bf16x8 a = *(const bf16x8*)(embb + (m0 + col) * FEAT + kb + quad * 8);
        #pragma unroll
        for (int nt = 0; nt < 8; ++nt) {
            bf16x8 b = *(const bf16x8*)(Wr + (nt * 16 + col) * FEAT + kb + quad * 8);
            acc[nt] = __builtin_amdgcn_mfma_f32_16x16x32_bf16(a, b, acc[nt], 0, 0, 0);
        }
    }
    #pragma unroll
    for (int nt = 0; nt < 8; ++nt) {
        float bv = bias[nt * 16 + col];
        #pragma unroll
        for (int r = 0; r < 4; ++r) {
            float v = fmaxf(acc[nt][r] + bv, 0.f);
            hout[(m0 + quad * 4 + r) * HID + nt * 16 + col] = f2bf(v);
        }
    }
}

// ---------------- GEMM layer 2: out = mean2@W2l^T + b2l + h@W2r^T ----------
__global__ __launch_bounds__(256) void gemm2_kernel(
        const short* __restrict__ mean2, const short* __restrict__ hbf,
        const short* __restrict__ Wl, const short* __restrict__ Wr,
        const float* __restrict__ bias, float* __restrict__ out) {
    int wid = blockIdx.x * 4 + (threadIdx.x >> 6);
    if (wid >= N_NODES / 16) return;
    int lane = threadIdx.x & 63;
    int col = lane & 15, quad = lane >> 4;
    int m0 = wid * 16;
    f32x4 acc[8];
    #pragma unroll
    for (int nt = 0; nt < 8; ++nt) acc[nt] = (f32x4){0.f,0.f,0.f,0.f};
    #pragma unroll
    for (int kb = 0; kb < HID; kb += 32) {
        bf16x8 a = *(const bf16x8*)(mean2 + (m0 + col) * HID + kb + quad * 8);
        #pragma unroll
        for (int nt = 0; nt < 8; ++nt) {
            bf16x8 b = *(const bf16x8*)(Wl + (nt * 16 + col) * HID + kb + quad * 8);
            acc[nt] = __builtin_amdgcn_mfma_f32_16x16x32_bf16(a, b, acc[nt], 0, 0, 0);
        }
    }
    #pragma unroll
    for (int kb = 0; kb < HID; kb += 32) {
        bf16x8 a = *(const bf16x8*)(hbf + (m0 + col) * HID + kb + quad * 8);
        #pragma unroll
        for (int nt = 0; nt < 8; ++nt) {
            bf16x8 b = *(const bf16x8*)(Wr + (nt * 16 + col) * HID + kb + quad * 8);
            acc[nt] = __builtin_amdgcn_mfma_f32_16x16x32_bf16(a, b, acc[nt], 0, 0, 0);
        }
    }
    #pragma unroll
    for (int nt = 0; nt < 8; ++nt) {
        float bv = bias[nt * 16 + col];
        #pragma unroll
        for (int r = 0; r < 4; ++r) {
            out[(m0 + quad * 4 + r) * HID + nt * 16 + col] = acc[nt][r] + bv;
        }
    }
}

extern "C" void kernel_launch(void* const* d_in, const int* in_sizes, int n_in,
                              void* d_out, int out_size, void* d_ws, size_t ws_size,
                              hipStream_t stream) {
    const int*   edge_index = (const int*)d_in[0];
    const float* emb        = (const float*)d_in[1];
    const float* W1l        = (const float*)d_in[2];
    const float* b1l        = (const float*)d_in[3];
    const float* W1r        = (const float*)d_in[4];
    const float* W2l        = (const float*)d_in[5];
    const float* b2l        = (const float*)d_in[6];
    const float* W2r        = (const float*)d_in[7];
    float* out = (float*)d_out;

    const int* src = edge_index;
    const int* dst = edge_index + N_EDGES;

    // ---- ws layout (int-indexed; bf16 regions 16B-aligned), ~42 MB ----
    int* iws    = (int*)d_ws;
    int* offset = iws;                        // 50001 (+pad)
    int* count  = iws + 50004;                // 50000  -- zeroed
    int* cursor = iws + 100004;               // 50000  -- zeroed
    int* dhist  = iws + 150004;               // 64     -- zeroed
    int* dcur   = iws + 150068;               // 64     -- zeroed
    int* bsum   = iws + 150132;               // 256
    int* boff   = iws + 150388;               // 256
    int* dstart = iws + 150644;               // 64 (+pad to 150708... keep simple)
    int* perm   = iws + 150712;               // 50000
    int* esrc   = iws + 200712;               // 640000 -> 840712
    unsigned short* W1l_bf = (unsigned short*)(iws + 840712);   // 8192 bf16 (16B aligned)
    unsigned short* W1r_bf = (unsigned short*)(iws + 844808);   // 8192
    unsigned short* W2l_bf = (unsigned short*)(iws + 848904);   // 16384
    unsigned short* W2r_bf = (unsigned short*)(iws + 857096);   // 16384
    unsigned short* Wbf    = W1l_bf;                            // contiguous 49152
    unsigned short* emb_bf = (unsigned short*)(iws + 865288);   // 3.2M bf16
    unsigned short* mean1  = (unsigned short*)(iws + 2465288);  // 3.2M bf16
    unsigned short* hbf    = (unsigned short*)(iws + 4065288);  // 6.4M bf16
    unsigned short* mean2  = (unsigned short*)(iws + 7265288);  // 6.4M bf16

    // zero count/cursor/dhist/dcur (contiguous run)
    hipMemsetAsync(count, 0, (size_t)(150132 - 50004) * sizeof(int), stream);

    cvt_all_kernel<<<(N_NODES * FEAT + 49152 + 255) / 256, 256, 0, stream>>>(
        emb, W1l, W1r, W2l, W2r, emb_bf, Wbf);

    hist_kernel<<<(N_EDGES + 255) / 256, 256, 0, stream>>>(dst, count);
    scan1_kernel<<<NB, 256, 0, stream>>>(count, offset, bsum, dhist);
    scan2_kernel<<<2, 256, 0, stream>>>(bsum, boff, dhist, dstart);
    scan3_kernel<<<NB, 256, 0, stream>>>(offset, boff);
    fill_kernel<<<(N_EDGES + 255) / 256, 256, 0, stream>>>(src, dst, offset, cursor, esrc);
    permute_kernel<<<NB, 256, 0, stream>>>(count, dstart, dcur, perm);

    gather1_kernel<<<(N_NODES + 31) / 32, 256, 0, stream>>>(
        (const float4*)emb_bf, offset, esrc, perm, (uint4*)mean1);
    gemm1_kernel<<<(N_NODES / 16 + 3) / 4, 256, 0, stream>>>(
        (const short*)mean1, (const short*)emb_bf,
        (const short*)W1l_bf, (const short*)W1r_bf, b1l, hbf);
    gather2_kernel<<<(N_NODES + 15) / 16, 256, 0, stream>>>(
        (const float4*)hbf, offset, esrc, perm, (uint4*)mean2);
    gemm2_kernel<<<(N_NODES / 16 + 3) / 4, 256, 0, stream>>>(
        (const short*)mean2, (const short*)hbf,
        (const short*)W2l_bf, (const short*)W2r_bf, b2l, out);
}